// Round 12
// baseline (3220.847 us; speedup 1.0000x reference)
//
#include <hip/hip_runtime.h>
#include <hip/hip_bf16.h>

#define NE 8
#define NT 512
#define DIN 7168
#define DINT 2048
#define BK 64

typedef __bf16 bf16x8 __attribute__((ext_vector_type(8)));
typedef float f32x4 __attribute__((ext_vector_type(4)));
typedef unsigned short ushort8v __attribute__((ext_vector_type(8)));

#define MFMA __builtin_amdgcn_mfma_f32_16x16x32_bf16

// XOR swizzle (T2): 16B granule within a 128B row XOR'd with row&7.
__device__ __forceinline__ int swz(int row, int k) {
    return (row << 6) + (((k >> 3) ^ (row & 7)) << 3) + (k & 7);
}

__device__ __forceinline__ unsigned short b16(float f) {
    return __builtin_bit_cast(unsigned short, (__bf16)f);
}
__device__ __forceinline__ ushort4 cvt4(float4 v) {
    ushort4 h;
    h.x = b16(v.x); h.y = b16(v.y); h.z = b16(v.z); h.w = b16(v.w);
    return h;
}
__device__ __forceinline__ ushort8v cvt8(float4 a, float4 b) {
    ushort8v h;
    h[0] = b16(a.x); h[1] = b16(a.y); h[2] = b16(a.z); h[3] = b16(a.w);
    h[4] = b16(b.x); h[5] = b16(b.y); h[6] = b16(b.z); h[7] = b16(b.w);
    return h;
}

// lgkm-only drain + raw barrier (T4: vmcnt stays in flight)
__device__ __forceinline__ void barrier_lgkm() {
    asm volatile("s_waitcnt lgkmcnt(0)" ::: "memory");
    __builtin_amdgcn_s_barrier();
}

// ---------------- Kernel A: gate+up ----------------
// BM=128 x BN=128, BK=64, 512 thr = 8 waves (4x2), wave-tile 32x64, dual acc
// (64 AGPR). Single-buffer 48 KB LDS -> 2 blocks/CU; grid (4,16,8) = 512
// blocks = EXACTLY 2/CU, ONE round, all-resident (L3 dedupes weights+x).
// bm-fastest: the 4 weight-panel sharers are consecutive blocks (no drift).
// Cross-block overlap: while one block stages/barriers, the co-resident
// block's MFMA burst fills the matrix pipe.
// Iter (R6 rhythm): write t (regs from prev iter) -> issue loads t+1 ->
// lgkm barrier -> compute t (setprio MFMA) -> lgkm barrier.
__global__ __launch_bounds__(512, 4) void ffn_gate_up(
    const float* __restrict__ x, const float* __restrict__ w1,
    const float* __restrict__ b1, const float* __restrict__ w3,
    const float* __restrict__ b3, unsigned short* __restrict__ g) {
    __shared__ unsigned short As[128 * BK];   // 16 KB
    __shared__ unsigned short B1s[128 * BK];  // 16 KB
    __shared__ unsigned short B3s[128 * BK];  // 16 KB

    const int tid = threadIdx.x;
    const int lane = tid & 63;
    const int wave = tid >> 6;                // 0..7
    const int wm = wave >> 1, wn = wave & 1;  // wave tile 32(M) x 64(N)
    const int e = blockIdx.z;
    const int bm = blockIdx.x * 128;  // tokens (fastest grid dim)
    const int bn = blockIdx.y * 128;  // F

    const char* xb = (const char*)x + ((size_t)e * NT * DIN + (size_t)bm * DIN) * 4;
    const char* w1c = (const char*)w1 + ((size_t)e * DINT * DIN + (size_t)bn * DIN) * 4;
    const char* w3c = (const char*)w3 + ((size_t)e * DINT * DIN + (size_t)bn * DIN) * 4;

    const int srow = tid >> 4;        // 0..31
    const int scol = (tid & 15) * 4;  // 0..60
    const int swb = swz(srow, scol);  // p-invariant ((p*32+srow)&7 == srow&7)

    int xo[4];  // 4 passes of 32 rows each; same pattern for all 3 streams
#pragma unroll
    for (int p = 0; p < 4; ++p) xo[p] = ((p * 32 + srow) * DIN + scol) * 4;

    f32x4 acc1[2][4], acc3[2][4];  // 64 AGPR
#pragma unroll
    for (int m = 0; m < 2; ++m)
#pragma unroll
        for (int n = 0; n < 4; ++n) {
            acc1[m][n] = (f32x4)0.0f;
            acc3[m][n] = (f32x4)0.0f;
        }

    float4 ra[4], rb1[4], rb3[4];  // 48 VGPR in flight

    // prologue: issue tile-0 loads (all 3 streams)
#pragma unroll
    for (int p = 0; p < 4; ++p) {
        ra[p] = *(const float4*)(xb + xo[p]);
        rb1[p] = *(const float4*)(w1c + xo[p]);
        rb3[p] = *(const float4*)(w3c + xo[p]);
    }

    const int l15 = lane & 15;
    const int kf0 = (lane >> 4) << 3;
    const int NIT = DIN / BK;  // 112

    for (int t = 0; t < NIT; ++t) {
        // 1. write tile t (regs issued a full iteration ago; per-reg vmcnt)
#pragma unroll
        for (int p = 0; p < 4; ++p) {
            *(ushort4*)&As[p * 2048 + swb] = cvt4(ra[p]);
            *(ushort4*)&B1s[p * 2048 + swb] = cvt4(rb1[p]);
            *(ushort4*)&B3s[p * 2048 + swb] = cvt4(rb3[p]);
        }
        // 2. issue loads for tile t+1 (in flight across barrier + compute)
        const int kldB = ((t + 1 < NIT) ? (t + 1) : (NIT - 1)) * BK * 4;
#pragma unroll
        for (int p = 0; p < 4; ++p) {
            ra[p] = *(const float4*)(xb + xo[p] + kldB);
            rb1[p] = *(const float4*)(w1c + xo[p] + kldB);
            rb3[p] = *(const float4*)(w3c + xo[p] + kldB);
        }
        // 3. barrier: drain LDS writes only; global loads stay in flight
        barrier_lgkm();
        // 4. compute
#pragma unroll
        for (int ks = 0; ks < 2; ++ks) {
            const int kf = ks * 32 + kf0;
            bf16x8 af[2], b1f[4], b3f[4];
#pragma unroll
            for (int m = 0; m < 2; ++m)
                af[m] = *(const bf16x8*)&As[swz(wm * 32 + m * 16 + l15, kf)];
#pragma unroll
            for (int n = 0; n < 4; ++n) {
                b1f[n] = *(const bf16x8*)&B1s[swz(wn * 64 + n * 16 + l15, kf)];
                b3f[n] = *(const bf16x8*)&B3s[swz(wn * 64 + n * 16 + l15, kf)];
            }
            __builtin_amdgcn_s_setprio(1);
#pragma unroll
            for (int n = 0; n < 4; ++n)
#pragma unroll
                for (int m = 0; m < 2; ++m) {
                    acc1[m][n] = MFMA(af[m], b1f[n], acc1[m][n], 0, 0, 0);
                    acc3[m][n] = MFMA(af[m], b3f[n], acc3[m][n], 0, 0, 0);
                }
            __builtin_amdgcn_s_setprio(0);
        }
        // 5. post-compute barrier (reads done before next overwrite)
        barrier_lgkm();
    }

    // epilogue: bias + silu*mul -> bf16 g
    float bias1[4], bias3[4];
#pragma unroll
    for (int n = 0; n < 4; ++n) {
        const int f = bn + wn * 64 + n * 16 + l15;
        bias1[n] = b1[e * DINT + f];
        bias3[n] = b3[e * DINT + f];
    }
#pragma unroll
    for (int m = 0; m < 2; ++m)
#pragma unroll
        for (int n = 0; n < 4; ++n) {
            const int f = bn + wn * 64 + n * 16 + l15;
#pragma unroll
            for (int j = 0; j < 4; ++j) {
                const int t = bm + wm * 32 + m * 16 + ((lane >> 4) << 2) + j;
                const float h1 = acc1[m][n][j] + bias1[n];
                const float h3 = acc3[m][n][j] + bias3[n];
                const float sg = h1 / (1.0f + __expf(-h1));
                g[(size_t)e * NT * DINT + (size_t)t * DINT + f] =
                    __builtin_bit_cast(unsigned short, (__bf16)(sg * h3));
            }
        }
}

// ---------------- Kernel B: down (R6 version, proven 153 us) ----------------
// BM=256 x BN=128, 512 thr, wave 64x64. grid (56,2,8)=896. dbuf 96 KB.
// 2 phases per K-tile, each 16 MFMA + half the staging.
__global__ __launch_bounds__(512, 2) void ffn_down(
    const unsigned short* __restrict__ g, const float* __restrict__ w2,
    const float* __restrict__ b2, float* __restrict__ out) {
    __shared__ unsigned short As[2][256 * BK];  // 64 KB
    __shared__ unsigned short Bs[2][128 * BK];  // 32 KB

    const int tid = threadIdx.x;
    const int lane = tid & 63;
    const int wave = tid >> 6;
    const int wm = wave >> 1, wn = wave & 1;
    const int e = blockIdx.z;
    const int bn = blockIdx.x * 128;
    const int bm = blockIdx.y * 256;

    const char* gc = (const char*)g + ((size_t)e * NT * DINT + (size_t)bm * DINT) * 2;
    const char* w2c = (const char*)w2 + ((size_t)e * DIN * DINT + (size_t)bn * DINT) * 4;

    const int arow = tid >> 3;          // 0..63
    const int acol = (tid & 7) * 8;     // bf16 elems
    const int brow = tid >> 4;          // 0..31
    const int bcol = (tid & 15) * 4;
    const int swA = swz(arow, acol);    // p-invariant
    const int swB = swz(brow, bcol);

    int go[4], wo[4];
#pragma unroll
    for (int p = 0; p < 4; ++p) {
        go[p] = ((p * 64 + arow) * DINT + acol) * 2;
        wo[p] = ((p * 32 + brow) * DINT + bcol) * 4;
    }

    f32x4 acc[4][4];
#pragma unroll
    for (int m = 0; m < 4; ++m)
#pragma unroll
        for (int n = 0; n < 4; ++n) acc[m][n] = (f32x4)0.0f;

    ushort8v ga[4];
    float4 rb[4];

#pragma unroll
    for (int p = 0; p < 4; ++p) ga[p] = *(const ushort8v*)(gc + go[p]);
#pragma unroll
    for (int p = 0; p < 4; ++p) rb[p] = *(const float4*)(w2c + wo[p]);
#pragma unroll
    for (int p = 0; p < 4; ++p) *(ushort8v*)&As[0][p * 4096 + swA] = ga[p];
#pragma unroll
    for (int p = 0; p < 4; ++p) *(ushort4*)&Bs[0][p * 2048 + swB] = cvt4(rb[p]);
#pragma unroll
    for (int p = 0; p < 4; ++p) ga[p] = *(const ushort8v*)(gc + go[p] + BK * 2);
#pragma unroll
    for (int p = 0; p < 4; ++p) rb[p] = *(const float4*)(w2c + wo[p] + BK * 4);
    barrier_lgkm();

    const int l15 = lane & 15;
    const int kf0 = (lane >> 4) << 3;

    int cur = 0;
    const int NIT = DINT / BK;  // 32
    for (int t = 0; t < NIT; ++t) {
        const int nxt = cur ^ 1;
        const int kld = (t + 2 < NIT) ? (t + 2) * BK : (NIT - 1) * BK;
        const bool stage = (t < NIT - 1);
        bf16x8 af[4], bf[4];

        // ---- Phase 0: ks0 ----
#pragma unroll
        for (int m = 0; m < 4; ++m)
            af[m] = *(const bf16x8*)&As[cur][swz(wm * 64 + m * 16 + l15, kf0)];
#pragma unroll
        for (int n = 0; n < 4; ++n)
            bf[n] = *(const bf16x8*)&Bs[cur][swz(wn * 64 + n * 16 + l15, kf0)];
        if (stage) {
#pragma unroll
            for (int p = 0; p < 4; ++p) *(ushort8v*)&As[nxt][p * 4096 + swA] = ga[p];
#pragma unroll
            for (int p = 0; p < 4; ++p) ga[p] = *(const ushort8v*)(gc + go[p] + kld * 2);
        }
        __builtin_amdgcn_s_setprio(1);
#pragma unroll
        for (int n = 0; n < 4; ++n)
#pragma unroll
            for (int m = 0; m < 4; ++m)
                acc[m][n] = MFMA(af[m], bf[n], acc[m][n], 0, 0, 0);
        __builtin_amdgcn_s_setprio(0);
        __builtin_amdgcn_sched_barrier(0);

        // ---- Phase 1: ks1 ----
#pragma unroll
        for (int m = 0; m < 4; ++m)
            af[m] = *(const bf16x8*)&As[cur][swz(wm * 64 + m * 16 + l15, 32 + kf0)];
#pragma unroll
        for (int n = 0; n < 4; ++n)
            bf[n] = *(const bf16x8*)&Bs[cur][swz(wn * 64 + n * 16 + l15, 32 + kf0)];
        if (stage) {
#pragma unroll
            for (int p = 0; p < 4; ++p) *(ushort4*)&Bs[nxt][p * 2048 + swB] = cvt4(rb[p]);
#pragma unroll
            for (int p = 0; p < 4; ++p) rb[p] = *(const float4*)(w2c + wo[p] + kld * 4);
        }
        __builtin_amdgcn_s_setprio(1);
#pragma unroll
        for (int n = 0; n < 4; ++n)
#pragma unroll
            for (int m = 0; m < 4; ++m)
                acc[m][n] = MFMA(af[m], bf[n], acc[m][n], 0, 0, 0);
        __builtin_amdgcn_s_setprio(0);

        barrier_lgkm();
        cur = nxt;
    }

    float bias[4];
#pragma unroll
    for (int n = 0; n < 4; ++n) {
        const int d = bn + wn * 64 + n * 16 + l15;
        bias[n] = b2[e * DIN + d];
    }
#pragma unroll
    for (int m = 0; m < 4; ++m)
#pragma unroll
        for (int n = 0; n < 4; ++n) {
            const int d = bn + wn * 64 + n * 16 + l15;
#pragma unroll
            for (int j = 0; j < 4; ++j) {
                const int t = bm + wm * 64 + m * 16 + ((lane >> 4) << 2) + j;
                out[(size_t)e * NT * DIN + (size_t)t * DIN + d] = acc[m][n][j] + bias[n];
            }
        }
}

extern "C" void kernel_launch(void* const* d_in, const int* in_sizes, int n_in,
                              void* d_out, int out_size, void* d_ws, size_t ws_size,
                              hipStream_t stream) {
    const float* x = (const float*)d_in[0];
    const float* w1 = (const float*)d_in[1];
    const float* b1 = (const float*)d_in[2];
    const float* w3 = (const float*)d_in[3];
    const float* b3 = (const float*)d_in[4];
    const float* w2 = (const float*)d_in[5];
    const float* b2 = (const float*)d_in[6];
    float* out = (float*)d_out;
    unsigned short* g = (unsigned short*)d_ws;  // [E][T][DINT] bf16

    // gate: bm-fastest, 512 blocks = exactly 2/CU, one round, all-resident
    dim3 gridA(NT / 128, DINT / 128, NE);  // (4, 16, 8) = 512 blocks
    dim3 gridB(DIN / 128, NT / 256, NE);   // (56, 2, 8) = 896 blocks
    ffn_gate_up<<<gridA, dim3(512), 0, stream>>>(x, w1, b1, w3, b3, g);
    ffn_down<<<gridB, dim3(512), 0, stream>>>(g, w2, b2, out);
}

// Round 13
// 2068.047 us; speedup vs baseline: 1.5574x; 1.5574x over previous
//
#include <hip/hip_runtime.h>
#include <hip/hip_bf16.h>

#define NE 8
#define NT 512
#define DIN 7168
#define DINT 2048
#define BK 64

typedef __bf16 bf16x8 __attribute__((ext_vector_type(8)));
typedef float f32x4 __attribute__((ext_vector_type(4)));
typedef unsigned short ushort8v __attribute__((ext_vector_type(8)));

#define MFMA __builtin_amdgcn_mfma_f32_16x16x32_bf16

// XOR swizzle (T2): 16B granule within a 128B row XOR'd with row&7.
__device__ __forceinline__ int swz(int row, int k) {
    return (row << 6) + (((k >> 3) ^ (row & 7)) << 3) + (k & 7);
}

__device__ __forceinline__ unsigned short b16(float f) {
    return __builtin_bit_cast(unsigned short, (__bf16)f);
}
__device__ __forceinline__ ushort4 cvt4(float4 v) {
    ushort4 h;
    h.x = b16(v.x); h.y = b16(v.y); h.z = b16(v.z); h.w = b16(v.w);
    return h;
}
__device__ __forceinline__ ushort8v cvt8(float4 a, float4 b) {
    ushort8v h;
    h[0] = b16(a.x); h[1] = b16(a.y); h[2] = b16(a.z); h[3] = b16(a.w);
    h[4] = b16(b.x); h[5] = b16(b.y); h[6] = b16(b.z); h[7] = b16(b.w);
    return h;
}

// lgkm-only drain + raw barrier (T4: vmcnt stays in flight)
__device__ __forceinline__ void barrier_lgkm() {
    asm volatile("s_waitcnt lgkmcnt(0)" ::: "memory");
    __builtin_amdgcn_s_barrier();
}

// ---------------- Kernel A: gate+up ----------------
// BM=128 x BN=128, BK=64, 256 thr = 4 waves (2x2), wave-tile 64x64, dual acc
// (128 AGPR). Register budget: acc 128 + prefetch 96 + addr ~20 = ~244,
// cap at 2 waves/EU (8 waves/CU = 2 blocks/CU) = 256 -> fits, no spill.
// Single-buffer 48 KB LDS -> 2 blocks/CU. grid (4,16,8) = 512 = exactly
// 2/CU, ONE round, all-resident -> L3 dedupes weights (FETCH ~920 MB).
// bm-fastest. ALL THREE streams cross-iter prefetched (R8/R9 fix).
// Iter (R6 rhythm): write t (regs from iter t-1) -> issue loads t+1 ->
// lgkm barrier -> compute t (setprio MFMA) -> lgkm barrier.
__global__ __launch_bounds__(256, 2) void ffn_gate_up(
    const float* __restrict__ x, const float* __restrict__ w1,
    const float* __restrict__ b1, const float* __restrict__ w3,
    const float* __restrict__ b3, unsigned short* __restrict__ g) {
    __shared__ unsigned short As[128 * BK];   // 16 KB
    __shared__ unsigned short B1s[128 * BK];  // 16 KB
    __shared__ unsigned short B3s[128 * BK];  // 16 KB

    const int tid = threadIdx.x;
    const int lane = tid & 63;
    const int wave = tid >> 6;                // 0..3
    const int wm = wave >> 1, wn = wave & 1;  // wave tile 64x64
    const int e = blockIdx.z;
    const int bm = blockIdx.x * 128;  // tokens (fastest grid dim)
    const int bn = blockIdx.y * 128;  // F

    const char* xb = (const char*)x + ((size_t)e * NT * DIN + (size_t)bm * DIN) * 4;
    const char* w1c = (const char*)w1 + ((size_t)e * DINT * DIN + (size_t)bn * DIN) * 4;
    const char* w3c = (const char*)w3 + ((size_t)e * DINT * DIN + (size_t)bn * DIN) * 4;

    const int srow = tid >> 4;        // 0..15
    const int scol = (tid & 15) * 4;  // 0..60
    const int swb = swz(srow, scol);  // p-invariant ((p*16+srow)&7 == srow&7)

    int xo[8];  // 8 passes of 16 rows; same pattern for all 3 streams
#pragma unroll
    for (int p = 0; p < 8; ++p) xo[p] = ((p * 16 + srow) * DIN + scol) * 4;

    f32x4 acc1[4][4], acc3[4][4];  // 128 AGPR
#pragma unroll
    for (int m = 0; m < 4; ++m)
#pragma unroll
        for (int n = 0; n < 4; ++n) {
            acc1[m][n] = (f32x4)0.0f;
            acc3[m][n] = (f32x4)0.0f;
        }

    float4 ra[8], rb1[8], rb3[8];  // 96 VGPR in flight

    // prologue: issue tile-0 loads (all 3 streams)
#pragma unroll
    for (int p = 0; p < 8; ++p) {
        ra[p] = *(const float4*)(xb + xo[p]);
        rb1[p] = *(const float4*)(w1c + xo[p]);
        rb3[p] = *(const float4*)(w3c + xo[p]);
    }

    const int l15 = lane & 15;
    const int kf0 = (lane >> 4) << 3;
    const int NIT = DIN / BK;  // 112

    for (int t = 0; t < NIT; ++t) {
        // 1. write tile t (regs issued a full iteration ago; per-reg vmcnt)
#pragma unroll
        for (int p = 0; p < 8; ++p) {
            *(ushort4*)&As[p * 1024 + swb] = cvt4(ra[p]);
            *(ushort4*)&B1s[p * 1024 + swb] = cvt4(rb1[p]);
            *(ushort4*)&B3s[p * 1024 + swb] = cvt4(rb3[p]);
        }
        // 2. issue loads for tile t+1 (in flight across barrier + compute)
        const int kldB = ((t + 1 < NIT) ? (t + 1) : (NIT - 1)) * BK * 4;
#pragma unroll
        for (int p = 0; p < 8; ++p) {
            ra[p] = *(const float4*)(xb + xo[p] + kldB);
            rb1[p] = *(const float4*)(w1c + xo[p] + kldB);
            rb3[p] = *(const float4*)(w3c + xo[p] + kldB);
        }
        // 3. barrier: drain LDS writes only; global loads stay in flight
        barrier_lgkm();
        // 4. compute
#pragma unroll
        for (int ks = 0; ks < 2; ++ks) {
            const int kf = ks * 32 + kf0;
            bf16x8 af[4], b1f[4], b3f[4];
#pragma unroll
            for (int m = 0; m < 4; ++m)
                af[m] = *(const bf16x8*)&As[swz(wm * 64 + m * 16 + l15, kf)];
#pragma unroll
            for (int n = 0; n < 4; ++n) {
                b1f[n] = *(const bf16x8*)&B1s[swz(wn * 64 + n * 16 + l15, kf)];
                b3f[n] = *(const bf16x8*)&B3s[swz(wn * 64 + n * 16 + l15, kf)];
            }
            __builtin_amdgcn_s_setprio(1);
#pragma unroll
            for (int n = 0; n < 4; ++n)
#pragma unroll
                for (int m = 0; m < 4; ++m) {
                    acc1[m][n] = MFMA(af[m], b1f[n], acc1[m][n], 0, 0, 0);
                    acc3[m][n] = MFMA(af[m], b3f[n], acc3[m][n], 0, 0, 0);
                }
            __builtin_amdgcn_s_setprio(0);
        }
        // 5. post-compute barrier (reads done before next overwrite)
        barrier_lgkm();
    }

    // epilogue: bias + silu*mul -> bf16 g
    float bias1[4], bias3[4];
#pragma unroll
    for (int n = 0; n < 4; ++n) {
        const int f = bn + wn * 64 + n * 16 + l15;
        bias1[n] = b1[e * DINT + f];
        bias3[n] = b3[e * DINT + f];
    }
#pragma unroll
    for (int m = 0; m < 4; ++m)
#pragma unroll
        for (int n = 0; n < 4; ++n) {
            const int f = bn + wn * 64 + n * 16 + l15;
#pragma unroll
            for (int j = 0; j < 4; ++j) {
                const int t = bm + wm * 64 + m * 16 + ((lane >> 4) << 2) + j;
                const float h1 = acc1[m][n][j] + bias1[n];
                const float h3 = acc3[m][n][j] + bias3[n];
                const float sg = h1 / (1.0f + __expf(-h1));
                g[(size_t)e * NT * DINT + (size_t)t * DINT + f] =
                    __builtin_bit_cast(unsigned short, (__bf16)(sg * h3));
            }
        }
}

// ---------------- Kernel B: down (R6 version, proven 153 us) ----------------
// BM=256 x BN=128, 512 thr, wave 64x64. grid (56,2,8)=896. dbuf 96 KB.
// 2 phases per K-tile, each 16 MFMA + half the staging.
__global__ __launch_bounds__(512, 2) void ffn_down(
    const unsigned short* __restrict__ g, const float* __restrict__ w2,
    const float* __restrict__ b2, float* __restrict__ out) {
    __shared__ unsigned short As[2][256 * BK];  // 64 KB
    __shared__ unsigned short Bs[2][128 * BK];  // 32 KB

    const int tid = threadIdx.x;
    const int lane = tid & 63;
    const int wave = tid >> 6;
    const int wm = wave >> 1, wn = wave & 1;
    const int e = blockIdx.z;
    const int bn = blockIdx.x * 128;
    const int bm = blockIdx.y * 256;

    const char* gc = (const char*)g + ((size_t)e * NT * DINT + (size_t)bm * DINT) * 2;
    const char* w2c = (const char*)w2 + ((size_t)e * DIN * DINT + (size_t)bn * DINT) * 4;

    const int arow = tid >> 3;          // 0..63
    const int acol = (tid & 7) * 8;     // bf16 elems
    const int brow = tid >> 4;          // 0..31
    const int bcol = (tid & 15) * 4;
    const int swA = swz(arow, acol);    // p-invariant
    const int swB = swz(brow, bcol);

    int go[4], wo[4];
#pragma unroll
    for (int p = 0; p < 4; ++p) {
        go[p] = ((p * 64 + arow) * DINT + acol) * 2;
        wo[p] = ((p * 32 + brow) * DINT + bcol) * 4;
    }

    f32x4 acc[4][4];
#pragma unroll
    for (int m = 0; m < 4; ++m)
#pragma unroll
        for (int n = 0; n < 4; ++n) acc[m][n] = (f32x4)0.0f;

    ushort8v ga[4];
    float4 rb[4];

#pragma unroll
    for (int p = 0; p < 4; ++p) ga[p] = *(const ushort8v*)(gc + go[p]);
#pragma unroll
    for (int p = 0; p < 4; ++p) rb[p] = *(const float4*)(w2c + wo[p]);
#pragma unroll
    for (int p = 0; p < 4; ++p) *(ushort8v*)&As[0][p * 4096 + swA] = ga[p];
#pragma unroll
    for (int p = 0; p < 4; ++p) *(ushort4*)&Bs[0][p * 2048 + swB] = cvt4(rb[p]);
#pragma unroll
    for (int p = 0; p < 4; ++p) ga[p] = *(const ushort8v*)(gc + go[p] + BK * 2);
#pragma unroll
    for (int p = 0; p < 4; ++p) rb[p] = *(const float4*)(w2c + wo[p] + BK * 4);
    barrier_lgkm();

    const int l15 = lane & 15;
    const int kf0 = (lane >> 4) << 3;

    int cur = 0;
    const int NIT = DINT / BK;  // 32
    for (int t = 0; t < NIT; ++t) {
        const int nxt = cur ^ 1;
        const int kld = (t + 2 < NIT) ? (t + 2) * BK : (NIT - 1) * BK;
        const bool stage = (t < NIT - 1);
        bf16x8 af[4], bf[4];

        // ---- Phase 0: ks0 ----
#pragma unroll
        for (int m = 0; m < 4; ++m)
            af[m] = *(const bf16x8*)&As[cur][swz(wm * 64 + m * 16 + l15, kf0)];
#pragma unroll
        for (int n = 0; n < 4; ++n)
            bf[n] = *(const bf16x8*)&Bs[cur][swz(wn * 64 + n * 16 + l15, kf0)];
        if (stage) {
#pragma unroll
            for (int p = 0; p < 4; ++p) *(ushort8v*)&As[nxt][p * 4096 + swA] = ga[p];
#pragma unroll
            for (int p = 0; p < 4; ++p) ga[p] = *(const ushort8v*)(gc + go[p] + kld * 2);
        }
        __builtin_amdgcn_s_setprio(1);
#pragma unroll
        for (int n = 0; n < 4; ++n)
#pragma unroll
            for (int m = 0; m < 4; ++m)
                acc[m][n] = MFMA(af[m], bf[n], acc[m][n], 0, 0, 0);
        __builtin_amdgcn_s_setprio(0);
        __builtin_amdgcn_sched_barrier(0);

        // ---- Phase 1: ks1 ----
#pragma unroll
        for (int m = 0; m < 4; ++m)
            af[m] = *(const bf16x8*)&As[cur][swz(wm * 64 + m * 16 + l15, 32 + kf0)];
#pragma unroll
        for (int n = 0; n < 4; ++n)
            bf[n] = *(const bf16x8*)&Bs[cur][swz(wn * 64 + n * 16 + l15, 32 + kf0)];
        if (stage) {
#pragma unroll
            for (int p = 0; p < 4; ++p) *(ushort4*)&Bs[nxt][p * 2048 + swB] = cvt4(rb[p]);
#pragma unroll
            for (int p = 0; p < 4; ++p) rb[p] = *(const float4*)(w2c + wo[p] + kld * 4);
        }
        __builtin_amdgcn_s_setprio(1);
#pragma unroll
        for (int n = 0; n < 4; ++n)
#pragma unroll
            for (int m = 0; m < 4; ++m)
                acc[m][n] = MFMA(af[m], bf[n], acc[m][n], 0, 0, 0);
        __builtin_amdgcn_s_setprio(0);

        barrier_lgkm();
        cur = nxt;
    }

    float bias[4];
#pragma unroll
    for (int n = 0; n < 4; ++n) {
        const int d = bn + wn * 64 + n * 16 + l15;
        bias[n] = b2[e * DIN + d];
    }
#pragma unroll
    for (int m = 0; m < 4; ++m)
#pragma unroll
        for (int n = 0; n < 4; ++n) {
            const int d = bn + wn * 64 + n * 16 + l15;
#pragma unroll
            for (int j = 0; j < 4; ++j) {
                const int t = bm + wm * 64 + m * 16 + ((lane >> 4) << 2) + j;
                out[(size_t)e * NT * DIN + (size_t)t * DIN + d] = acc[m][n][j] + bias[n];
            }
        }
}

extern "C" void kernel_launch(void* const* d_in, const int* in_sizes, int n_in,
                              void* d_out, int out_size, void* d_ws, size_t ws_size,
                              hipStream_t stream) {
    const float* x = (const float*)d_in[0];
    const float* w1 = (const float*)d_in[1];
    const float* b1 = (const float*)d_in[2];
    const float* w3 = (const float*)d_in[3];
    const float* b3 = (const float*)d_in[4];
    const float* w2 = (const float*)d_in[5];
    const float* b2 = (const float*)d_in[6];
    float* out = (float*)d_out;
    unsigned short* g = (unsigned short*)d_ws;  // [E][T][DINT] bf16

    // gate: bm-fastest, 512 blocks = exactly 2/CU, one round, all-resident
    dim3 gridA(NT / 128, DINT / 128, NE);  // (4, 16, 8) = 512 blocks
    dim3 gridB(DIN / 128, NT / 256, NE);   // (56, 2, 8) = 896 blocks
    ffn_gate_up<<<gridA, dim3(256), 0, stream>>>(x, w1, b1, w3, b3, g);
    ffn_down<<<gridB, dim3(512), 0, stream>>>(g, w2, b2, out);
}

// Round 14
// 546.088 us; speedup vs baseline: 5.8980x; 3.7870x over previous
//
#include <hip/hip_runtime.h>
#include <hip/hip_bf16.h>

#define NE 8
#define NT 512
#define DIN 7168
#define DINT 2048
#define BK 64

typedef __bf16 bf16x8 __attribute__((ext_vector_type(8)));
typedef float f32x4 __attribute__((ext_vector_type(4)));
typedef unsigned short ushort8v __attribute__((ext_vector_type(8)));

#define MFMA __builtin_amdgcn_mfma_f32_16x16x32_bf16

// XOR swizzle (T2): 16B granule within a 128B row XOR'd with row&7.
__device__ __forceinline__ int swz(int row, int k) {
    return (row << 6) + (((k >> 3) ^ (row & 7)) << 3) + (k & 7);
}

__device__ __forceinline__ unsigned short b16(float f) {
    return __builtin_bit_cast(unsigned short, (__bf16)f);
}
__device__ __forceinline__ ushort4 cvt4(float4 v) {
    ushort4 h;
    h.x = b16(v.x); h.y = b16(v.y); h.z = b16(v.z); h.w = b16(v.w);
    return h;
}
__device__ __forceinline__ ushort8v cvt8(float4 a, float4 b) {
    ushort8v h;
    h[0] = b16(a.x); h[1] = b16(a.y); h[2] = b16(a.z); h[3] = b16(a.w);
    h[4] = b16(b.x); h[5] = b16(b.y); h[6] = b16(b.z); h[7] = b16(b.w);
    return h;
}

// lgkm-only drain + raw barrier (T4: vmcnt stays in flight)
__device__ __forceinline__ void barrier_lgkm() {
    asm volatile("s_waitcnt lgkmcnt(0)" ::: "memory");
    __builtin_amdgcn_s_barrier();
}

// ---------------- Kernel A: gate+up (R6 structure + XCD=expert swizzle) ----
// BM=256 x BN=128, BK=64, 512 thr = 8 waves (4x2), wave 64x64, dual acc.
// 1D grid 256 blocks = 1/CU. XCD placement: linear bid round-robins XCDs,
// so bid&7 == XCD; decode e = bid&7 -> ALL blocks of expert e on XCD e:
// x (14.7 MB/expert) becomes XCD-L2-served after first touch; weight
// bm-twins co-XCD -> weights cross L3 once. Iter rhythm (proven R6):
// stage t+1 (regs from t-1) -> issue t+2 -> lgkm barrier (vmcnt in flight)
// -> setprio MFMA -> lgkm barrier. Per-phase split (4 phases).
__global__ __launch_bounds__(512, 2) void ffn_gate_up(
    const float* __restrict__ x, const float* __restrict__ w1,
    const float* __restrict__ b1, const float* __restrict__ w3,
    const float* __restrict__ b3, unsigned short* __restrict__ g) {
    __shared__ unsigned short As[2][256 * BK];   // 64 KB
    __shared__ unsigned short B1s[2][128 * BK];  // 32 KB
    __shared__ unsigned short B3s[2][128 * BK];  // 32 KB

    const int bid = blockIdx.x;
    const int e = bid & 7;        // XCD = bid % 8 (round-robin) -> expert pinned
    const int r = bid >> 3;       // 0..31
    const int bn = (r & 15) * 128;
    const int bm = (r >> 4) * 256;

    const int tid = threadIdx.x;
    const int lane = tid & 63;
    const int wave = tid >> 6;
    const int wm = wave >> 1, wn = wave & 1;

    const char* xb = (const char*)x + ((size_t)e * NT * DIN + (size_t)bm * DIN) * 4;
    const char* w1c = (const char*)w1 + ((size_t)e * DINT * DIN + (size_t)bn * DIN) * 4;
    const char* w3c = (const char*)w3 + ((size_t)e * DINT * DIN + (size_t)bn * DIN) * 4;

    const int srow = tid >> 4;          // 0..31
    const int scol = (tid & 15) * 4;    // 0..60
    const int swb = swz(srow, scol);    // p-invariant

    int xo[8];
#pragma unroll
    for (int p = 0; p < 8; ++p) xo[p] = ((p * 32 + srow) * DIN + scol) * 4;

    f32x4 acc1[4][4], acc3[4][4];
#pragma unroll
    for (int m = 0; m < 4; ++m)
#pragma unroll
        for (int n = 0; n < 4; ++n) {
            acc1[m][n] = (f32x4)0.0f;
            acc3[m][n] = (f32x4)0.0f;
        }

    float4 ra[8], rb1[4], rb3[4];

    // prologue: tile0 -> regs -> buf0; tile1 -> regs
#pragma unroll
    for (int p = 0; p < 8; ++p) ra[p] = *(const float4*)(xb + xo[p]);
#pragma unroll
    for (int p = 0; p < 4; ++p) {
        rb1[p] = *(const float4*)(w1c + xo[p]);
        rb3[p] = *(const float4*)(w3c + xo[p]);
    }
#pragma unroll
    for (int p = 0; p < 8; ++p) *(ushort4*)&As[0][p * 2048 + swb] = cvt4(ra[p]);
#pragma unroll
    for (int p = 0; p < 4; ++p) {
        *(ushort4*)&B1s[0][p * 2048 + swb] = cvt4(rb1[p]);
        *(ushort4*)&B3s[0][p * 2048 + swb] = cvt4(rb3[p]);
    }
#pragma unroll
    for (int p = 0; p < 8; ++p) ra[p] = *(const float4*)(xb + xo[p] + BK * 4);
#pragma unroll
    for (int p = 0; p < 4; ++p) {
        rb1[p] = *(const float4*)(w1c + xo[p] + BK * 4);
        rb3[p] = *(const float4*)(w3c + xo[p] + BK * 4);
    }
    barrier_lgkm();

    const int l15 = lane & 15;
    const int kf0 = (lane >> 4) << 3;

    int cur = 0;
    const int NIT = DIN / BK;  // 112
    for (int t = 0; t < NIT; ++t) {
        const int nxt = cur ^ 1;
        const int kldB = ((t + 2 < NIT) ? (t + 2) : (NIT - 1)) * BK * 4;
        const bool stage = (t < NIT - 1);
        bf16x8 af[4], bb[4];

        // ---- Phase 0: A@ks0 + B1@ks0 -> acc1 ----
#pragma unroll
        for (int m = 0; m < 4; ++m)
            af[m] = *(const bf16x8*)&As[cur][swz(wm * 64 + m * 16 + l15, kf0)];
#pragma unroll
        for (int n = 0; n < 4; ++n)
            bb[n] = *(const bf16x8*)&B1s[cur][swz(wn * 64 + n * 16 + l15, kf0)];
        if (stage) {
#pragma unroll
            for (int p = 0; p < 4; ++p) *(ushort4*)&As[nxt][p * 2048 + swb] = cvt4(ra[p]);
#pragma unroll
            for (int p = 0; p < 4; ++p) ra[p] = *(const float4*)(xb + xo[p] + kldB);
        }
        __builtin_amdgcn_s_setprio(1);
#pragma unroll
        for (int n = 0; n < 4; ++n)
#pragma unroll
            for (int m = 0; m < 4; ++m)
                acc1[m][n] = MFMA(af[m], bb[n], acc1[m][n], 0, 0, 0);
        __builtin_amdgcn_s_setprio(0);
        __builtin_amdgcn_sched_barrier(0);

        // ---- Phase 1: B3@ks0 -> acc3 (reuse af) ----
#pragma unroll
        for (int n = 0; n < 4; ++n)
            bb[n] = *(const bf16x8*)&B3s[cur][swz(wn * 64 + n * 16 + l15, kf0)];
        if (stage) {
#pragma unroll
            for (int p = 4; p < 8; ++p) *(ushort4*)&As[nxt][p * 2048 + swb] = cvt4(ra[p]);
#pragma unroll
            for (int p = 4; p < 8; ++p) ra[p] = *(const float4*)(xb + xo[p] + kldB);
        }
        __builtin_amdgcn_s_setprio(1);
#pragma unroll
        for (int n = 0; n < 4; ++n)
#pragma unroll
            for (int m = 0; m < 4; ++m)
                acc3[m][n] = MFMA(af[m], bb[n], acc3[m][n], 0, 0, 0);
        __builtin_amdgcn_s_setprio(0);
        __builtin_amdgcn_sched_barrier(0);

        // ---- Phase 2: A@ks1 + B1@ks1 -> acc1 ----
#pragma unroll
        for (int m = 0; m < 4; ++m)
            af[m] = *(const bf16x8*)&As[cur][swz(wm * 64 + m * 16 + l15, 32 + kf0)];
#pragma unroll
        for (int n = 0; n < 4; ++n)
            bb[n] = *(const bf16x8*)&B1s[cur][swz(wn * 64 + n * 16 + l15, 32 + kf0)];
        if (stage) {
#pragma unroll
            for (int p = 0; p < 4; ++p) *(ushort4*)&B1s[nxt][p * 2048 + swb] = cvt4(rb1[p]);
#pragma unroll
            for (int p = 0; p < 4; ++p) rb1[p] = *(const float4*)(w1c + xo[p] + kldB);
        }
        __builtin_amdgcn_s_setprio(1);
#pragma unroll
        for (int n = 0; n < 4; ++n)
#pragma unroll
            for (int m = 0; m < 4; ++m)
                acc1[m][n] = MFMA(af[m], bb[n], acc1[m][n], 0, 0, 0);
        __builtin_amdgcn_s_setprio(0);
        __builtin_amdgcn_sched_barrier(0);

        // ---- Phase 3: B3@ks1 -> acc3 ----
#pragma unroll
        for (int n = 0; n < 4; ++n)
            bb[n] = *(const bf16x8*)&B3s[cur][swz(wn * 64 + n * 16 + l15, 32 + kf0)];
        if (stage) {
#pragma unroll
            for (int p = 0; p < 4; ++p) *(ushort4*)&B3s[nxt][p * 2048 + swb] = cvt4(rb3[p]);
#pragma unroll
            for (int p = 0; p < 4; ++p) rb3[p] = *(const float4*)(w3c + xo[p] + kldB);
        }
        __builtin_amdgcn_s_setprio(1);
#pragma unroll
        for (int n = 0; n < 4; ++n)
#pragma unroll
            for (int m = 0; m < 4; ++m)
                acc3[m][n] = MFMA(af[m], bb[n], acc3[m][n], 0, 0, 0);
        __builtin_amdgcn_s_setprio(0);

        barrier_lgkm();
        cur = nxt;
    }

    // epilogue: bias + silu*mul -> bf16 g
    float bias1[4], bias3[4];
    const int l15e = lane & 15;
#pragma unroll
    for (int n = 0; n < 4; ++n) {
        const int f = bn + wn * 64 + n * 16 + l15e;
        bias1[n] = b1[e * DINT + f];
        bias3[n] = b3[e * DINT + f];
    }
#pragma unroll
    for (int m = 0; m < 4; ++m)
#pragma unroll
        for (int n = 0; n < 4; ++n) {
            const int f = bn + wn * 64 + n * 16 + l15e;
#pragma unroll
            for (int j = 0; j < 4; ++j) {
                const int t = bm + wm * 64 + m * 16 + ((lane >> 4) << 2) + j;
                const float h1 = acc1[m][n][j] + bias1[n];
                const float h3 = acc3[m][n][j] + bias3[n];
                const float sg = h1 / (1.0f + __expf(-h1));
                g[(size_t)e * NT * DINT + (size_t)t * DINT + f] =
                    __builtin_bit_cast(unsigned short, (__bf16)(sg * h3));
            }
        }
}

// ---------------- Kernel B: down (R6 structure + XCD=expert swizzle) -------
// BM=256 x BN=128, 512 thr, wave 64x64. 1D grid 896 blocks; e = bid&7 ->
// expert pinned to XCD: g (2.1 MB/expert) L2-resident, w2 twins co-XCD.
__global__ __launch_bounds__(512, 2) void ffn_down(
    const unsigned short* __restrict__ g, const float* __restrict__ w2,
    const float* __restrict__ b2, float* __restrict__ out) {
    __shared__ unsigned short As[2][256 * BK];  // 64 KB
    __shared__ unsigned short Bs[2][128 * BK];  // 32 KB

    const int bid = blockIdx.x;
    const int e = bid & 7;
    const int r = bid >> 3;         // 0..111
    const int bn = (r % 56) * 128;  // D offset
    const int bm = (r / 56) * 256;  // token offset

    const int tid = threadIdx.x;
    const int lane = tid & 63;
    const int wave = tid >> 6;
    const int wm = wave >> 1, wn = wave & 1;

    const char* gc = (const char*)g + ((size_t)e * NT * DINT + (size_t)bm * DINT) * 2;
    const char* w2c = (const char*)w2 + ((size_t)e * DIN * DINT + (size_t)bn * DINT) * 4;

    const int arow = tid >> 3;          // 0..63
    const int acol = (tid & 7) * 8;     // bf16 elems
    const int brow = tid >> 4;          // 0..31
    const int bcol = (tid & 15) * 4;
    const int swA = swz(arow, acol);    // p-invariant
    const int swB = swz(brow, bcol);

    int go[4], wo[4];
#pragma unroll
    for (int p = 0; p < 4; ++p) {
        go[p] = ((p * 64 + arow) * DINT + acol) * 2;
        wo[p] = ((p * 32 + brow) * DINT + bcol) * 4;
    }

    f32x4 acc[4][4];
#pragma unroll
    for (int m = 0; m < 4; ++m)
#pragma unroll
        for (int n = 0; n < 4; ++n) acc[m][n] = (f32x4)0.0f;

    ushort8v ga[4];
    float4 rb[4];

#pragma unroll
    for (int p = 0; p < 4; ++p) ga[p] = *(const ushort8v*)(gc + go[p]);
#pragma unroll
    for (int p = 0; p < 4; ++p) rb[p] = *(const float4*)(w2c + wo[p]);
#pragma unroll
    for (int p = 0; p < 4; ++p) *(ushort8v*)&As[0][p * 4096 + swA] = ga[p];
#pragma unroll
    for (int p = 0; p < 4; ++p) *(ushort4*)&Bs[0][p * 2048 + swB] = cvt4(rb[p]);
#pragma unroll
    for (int p = 0; p < 4; ++p) ga[p] = *(const ushort8v*)(gc + go[p] + BK * 2);
#pragma unroll
    for (int p = 0; p < 4; ++p) rb[p] = *(const float4*)(w2c + wo[p] + BK * 4);
    barrier_lgkm();

    const int l15 = lane & 15;
    const int kf0 = (lane >> 4) << 3;

    int cur = 0;
    const int NIT = DINT / BK;  // 32
    for (int t = 0; t < NIT; ++t) {
        const int nxt = cur ^ 1;
        const int kld = (t + 2 < NIT) ? (t + 2) * BK : (NIT - 1) * BK;
        const bool stage = (t < NIT - 1);
        bf16x8 af[4], bf[4];

        // ---- Phase 0: ks0 ----
#pragma unroll
        for (int m = 0; m < 4; ++m)
            af[m] = *(const bf16x8*)&As[cur][swz(wm * 64 + m * 16 + l15, kf0)];
#pragma unroll
        for (int n = 0; n < 4; ++n)
            bf[n] = *(const bf16x8*)&Bs[cur][swz(wn * 64 + n * 16 + l15, kf0)];
        if (stage) {
#pragma unroll
            for (int p = 0; p < 4; ++p) *(ushort8v*)&As[nxt][p * 4096 + swA] = ga[p];
#pragma unroll
            for (int p = 0; p < 4; ++p) ga[p] = *(const ushort8v*)(gc + go[p] + kld * 2);
        }
        __builtin_amdgcn_s_setprio(1);
#pragma unroll
        for (int n = 0; n < 4; ++n)
#pragma unroll
            for (int m = 0; m < 4; ++m)
                acc[m][n] = MFMA(af[m], bf[n], acc[m][n], 0, 0, 0);
        __builtin_amdgcn_s_setprio(0);
        __builtin_amdgcn_sched_barrier(0);

        // ---- Phase 1: ks1 ----
#pragma unroll
        for (int m = 0; m < 4; ++m)
            af[m] = *(const bf16x8*)&As[cur][swz(wm * 64 + m * 16 + l15, 32 + kf0)];
#pragma unroll
        for (int n = 0; n < 4; ++n)
            bf[n] = *(const bf16x8*)&Bs[cur][swz(wn * 64 + n * 16 + l15, 32 + kf0)];
        if (stage) {
#pragma unroll
            for (int p = 0; p < 4; ++p) *(ushort4*)&Bs[nxt][p * 2048 + swB] = cvt4(rb[p]);
#pragma unroll
            for (int p = 0; p < 4; ++p) rb[p] = *(const float4*)(w2c + wo[p] + kld * 4);
        }
        __builtin_amdgcn_s_setprio(1);
#pragma unroll
        for (int n = 0; n < 4; ++n)
#pragma unroll
            for (int m = 0; m < 4; ++m)
                acc[m][n] = MFMA(af[m], bf[n], acc[m][n], 0, 0, 0);
        __builtin_amdgcn_s_setprio(0);

        barrier_lgkm();
        cur = nxt;
    }

    float bias[4];
#pragma unroll
    for (int n = 0; n < 4; ++n) {
        const int d = bn + wn * 64 + n * 16 + l15;
        bias[n] = b2[e * DIN + d];
    }
#pragma unroll
    for (int m = 0; m < 4; ++m)
#pragma unroll
        for (int n = 0; n < 4; ++n) {
            const int d = bn + wn * 64 + n * 16 + l15;
#pragma unroll
            for (int j = 0; j < 4; ++j) {
                const int t = bm + wm * 64 + m * 16 + ((lane >> 4) << 2) + j;
                out[(size_t)e * NT * DIN + (size_t)t * DIN + d] = acc[m][n][j] + bias[n];
            }
        }
}

extern "C" void kernel_launch(void* const* d_in, const int* in_sizes, int n_in,
                              void* d_out, int out_size, void* d_ws, size_t ws_size,
                              hipStream_t stream) {
    const float* x = (const float*)d_in[0];
    const float* w1 = (const float*)d_in[1];
    const float* b1 = (const float*)d_in[2];
    const float* w3 = (const float*)d_in[3];
    const float* b3 = (const float*)d_in[4];
    const float* w2 = (const float*)d_in[5];
    const float* b2 = (const float*)d_in[6];
    float* out = (float*)d_out;
    unsigned short* g = (unsigned short*)d_ws;  // [E][T][DINT] bf16

    // 1D grids; bid&7 = XCD = expert (round-robin dispatch assumption; perf-only)
    ffn_gate_up<<<dim3(256), dim3(512), 0, stream>>>(x, w1, b1, w3, b3, g);
    ffn_down<<<dim3(896), dim3(512), 0, stream>>>(g, w2, b2, out);
}